// Round 7
// baseline (382.083 us; speedup 1.0000x reference)
//
#include <hip/hip_runtime.h>
#include <math.h>

constexpr int HD    = 32;     // head dim
constexpr int LW    = 256;    // tokens per window (M * N_CAND)
constexpr int NWIN  = 128;    // number of windows (= B_)
constexpr int ROWS  = NWIN * LW;   // 32768 total rows
constexpr int QKVC  = 384;    // qkv columns
constexpr float SCALE = 0.17677669529663687f;  // 1/sqrt(32)

__device__ inline float dot4(const float4 a, const float4 b) {
  return a.x * b.x + a.y * b.y + a.z * b.z + a.w * b.w;
}

// ---------------- RPE gather: rpe_g[h][i4*64+j4][0:96] ----------------
// s in [0,32): scale*q_rpe   [32,64): k_rpe   [64,96): v_rpe
__global__ __launch_bounds__(256) void rpe_gather_kernel(
    const float* __restrict__ tab, const int* __restrict__ rel_idx,
    float* __restrict__ out)
{
  int gid = blockIdx.x * 256 + threadIdx.x;   // 4*4096*96 = 1,572,864 exact
  int s   = gid % 96;
  int hp  = gid / 96;
  int p   = hp & 4095;
  int h   = hp >> 12;
  float v = tab[(size_t)rel_idx[p] * 384 + h * 96 + s];
  if (s < 32) v *= SCALE;
  out[gid] = v;
}

// ---------------- C[M,N] = A[M,K] @ W[N,K]^T + bias (LDS dbuf v3) -----------
template <int N, int K>
__global__ __launch_bounds__(256) void gemm_nt_bias_v3(
    const float* __restrict__ A, const float* __restrict__ W,
    const float* __restrict__ bias, float* __restrict__ C)
{
  constexpr int BK  = 8;
  constexpr int NS  = K / BK;
  constexpr int LDP = 144;
  __shared__ float As[2][BK][LDP];
  __shared__ float Ws[2][BK][LDP];

  const int tid  = threadIdx.x;
  const int tx   = tid & 15;          // n-dir, 8 cols each
  const int ty   = tid >> 4;          // m-dir, 8 rows each
  const int srow = tid >> 1;          // staging row 0..127
  const int skk  = (tid & 1) << 2;    // staging k base: 0 or 4
  const int sphys = srow + ((srow >> 5) << 2);

  const float* Ag = A + ((size_t)blockIdx.x * 128 + srow) * K + skk;
  const float* Wg = W + ((size_t)blockIdx.y * 128 + srow) * K + skk;

  float4 ra = *(const float4*)(Ag);
  float4 rw = *(const float4*)(Wg);
  As[0][skk + 0][sphys] = ra.x; As[0][skk + 1][sphys] = ra.y;
  As[0][skk + 2][sphys] = ra.z; As[0][skk + 3][sphys] = ra.w;
  Ws[0][skk + 0][sphys] = rw.x; Ws[0][skk + 1][sphys] = rw.y;
  Ws[0][skk + 2][sphys] = rw.z; Ws[0][skk + 3][sphys] = rw.w;
  __syncthreads();

  const int mA = ty * 8; const int pA = mA + ((mA >> 5) << 2);
  const int mB = tx * 8; const int pB = mB + ((mB >> 5) << 2);

  float acc[8][8] = {};

  for (int s = 0; s < NS; ++s) {
    const int cur = s & 1;
    if (s + 1 < NS) {
      const int k0 = (s + 1) * BK;
      ra = *(const float4*)(Ag + k0);
      rw = *(const float4*)(Wg + k0);
    }
#pragma unroll
    for (int k = 0; k < BK; ++k) {
      float4 a0 = *(const float4*)&As[cur][k][pA];
      float4 a1 = *(const float4*)&As[cur][k][pA + 4];
      float4 b0 = *(const float4*)&Ws[cur][k][pB];
      float4 b1 = *(const float4*)&Ws[cur][k][pB + 4];
      float av[8] = {a0.x, a0.y, a0.z, a0.w, a1.x, a1.y, a1.z, a1.w};
      float bv[8] = {b0.x, b0.y, b0.z, b0.w, b1.x, b1.y, b1.z, b1.w};
#pragma unroll
      for (int i = 0; i < 8; ++i)
#pragma unroll
        for (int j = 0; j < 8; ++j)
          acc[i][j] += av[i] * bv[j];
    }
    if (s + 1 < NS) {
      const int nxt = (s + 1) & 1;
      As[nxt][skk + 0][sphys] = ra.x; As[nxt][skk + 1][sphys] = ra.y;
      As[nxt][skk + 2][sphys] = ra.z; As[nxt][skk + 3][sphys] = ra.w;
      Ws[nxt][skk + 0][sphys] = rw.x; Ws[nxt][skk + 1][sphys] = rw.y;
      Ws[nxt][skk + 2][sphys] = rw.z; Ws[nxt][skk + 3][sphys] = rw.w;
      __syncthreads();
    }
  }

  const int crow = blockIdx.x * 128 + ty * 8;
  const int ccol = blockIdx.y * 128 + tx * 8;
  float4 bb0 = *(const float4*)(bias + ccol);
  float4 bb1 = *(const float4*)(bias + ccol + 4);
#pragma unroll
  for (int i = 0; i < 8; ++i) {
    float4 r0, r1;
    r0.x = acc[i][0] + bb0.x; r0.y = acc[i][1] + bb0.y;
    r0.z = acc[i][2] + bb0.z; r0.w = acc[i][3] + bb0.w;
    r1.x = acc[i][4] + bb1.x; r1.y = acc[i][5] + bb1.y;
    r1.z = acc[i][6] + bb1.z; r1.w = acc[i][7] + bb1.w;
    *(float4*)(C + (size_t)(crow + i) * N + ccol)     = r0;
    *(float4*)(C + (size_t)(crow + i) * N + ccol + 4) = r1;
  }
}

// ---------------- c0[b,h,i,j4] = SCALE * (q_i . k_rpe[i4,j4]) ----------------
// grid (64 i4, 4 h, 8 z) = 2048 blocks = 8/CU (v7's 4/CU was still
// latency-bound: serial 32-iter LDS-broadcast chains, ~35us each kernel).
// kr tile (64 j4 x 32) in LDS (8 KB). Thread t: rowid = t>>2 over this
// z-chunk's 16 windows x 4 ir; quarter = t&3 -> 16 j4 dots of K=32.
// Output layout [((b*4+h)*64 + j4)*256 + i]: attn reads 4B/lane coalesced.
__global__ __launch_bounds__(256) void c0_kernel(
    const float* __restrict__ qkv, const float* __restrict__ rpeg,
    float* __restrict__ c0L)
{
  __shared__ float krs[64 * 32];
  const int i4  = blockIdx.x;
  const int h   = blockIdx.y;
  const int z   = blockIdx.z;
  const int tid = threadIdx.x;
  for (int g = tid; g < 512; g += 256) {
    int j4 = g >> 3, c4 = g & 7;
    const float* src = rpeg + ((size_t)h * 4096 + i4 * 64 + j4) * 96 + 32 + c4 * 4;
    *(float4*)(&krs[j4 * 32 + c4 * 4]) = *(const float4*)src;
  }
  __syncthreads();

  const int rowid = tid >> 2;             // 0..63
  const int quart = tid & 3;              // j4 quarter
  const int b     = z * 16 + (rowid >> 2);
  const int ir    = rowid & 3;
  const int i     = i4 * 4 + ir;
  float4 q[8];
  {
    const float4* qr = (const float4*)(qkv + ((size_t)b * 256 + i) * QKVC + h * HD);
#pragma unroll
    for (int d = 0; d < 8; ++d) q[d] = qr[d];
  }
  float* o = c0L + ((size_t)(b * 4 + h) * 64) * 256 + i;
#pragma unroll 4
  for (int jj = 0; jj < 16; ++jj) {
    const int j4 = quart * 16 + jj;
    const float4* kr = (const float4*)(&krs[j4 * 32]);
    float d0 = 0.f;
#pragma unroll
    for (int d = 0; d < 8; ++d) d0 += dot4(q[d], kr[d]);
    o[j4 * 256] = d0 * SCALE;
  }
}

// ---------------- t[b,h,j,i4] = k_j . (SCALE*q_rpe[i4,j4]) ----------------
// grid (64 j4, 4 h, 8 z) = 2048 blocks = 8/CU. sq tile (64 i4 x 32) in LDS.
// Thread t: rowid = t>>2 over 16 windows x 4 jc; quarter = t&3 -> 16 i4.
// Output layout [((b*4+h)*64 + i4)*256 + j]: attn reads a float4 at
// j = j4*4 (16B broadcast per 4 lanes, same pattern as the mask read).
__global__ __launch_bounds__(256) void t_kernel(
    const float* __restrict__ qkv, const float* __restrict__ rpeg,
    float* __restrict__ tL)
{
  __shared__ float sqs[64 * 32];
  const int j4  = blockIdx.x;
  const int h   = blockIdx.y;
  const int z   = blockIdx.z;
  const int tid = threadIdx.x;
  for (int g = tid; g < 512; g += 256) {
    int i4 = g >> 3, c4 = g & 7;
    const float* src = rpeg + ((size_t)h * 4096 + i4 * 64 + j4) * 96 + c4 * 4;
    *(float4*)(&sqs[i4 * 32 + c4 * 4]) = *(const float4*)src;
  }
  __syncthreads();

  const int rowid = tid >> 2;
  const int quart = tid & 3;
  const int b     = z * 16 + (rowid >> 2);
  const int jc    = rowid & 3;
  const int j     = j4 * 4 + jc;
  float4 k[8];
  {
    const float4* kr = (const float4*)(qkv + ((size_t)b * 256 + j) * QKVC + 128 + h * HD);
#pragma unroll
    for (int d = 0; d < 8; ++d) k[d] = kr[d];
  }
  float* o = tL + ((size_t)(b * 4 + h) * 64) * 256 + j;
#pragma unroll 4
  for (int ii = 0; ii < 16; ++ii) {
    const int i4 = quart * 16 + ii;
    const float4* sq = (const float4*)(&sqs[i4 * 32]);
    float d0 = 0.f;
#pragma unroll
    for (int d = 0; d < 8; ++d) d0 += dot4(k[d], sq[d]);
    o[i4 * 256] = d0;
  }
}

// ------------- fused window attention (v8: branchless, pipelined) ----------
// grid (NWIN, 4 heads), 256 threads = one query row each.
// Static-max softmax (scores |s| <~ 1): p = __expf(s) directly. Masked
// entries: __expf(-1e9) = 0 exactly -- so the skip branch is REMOVED
// entirely (v7's `continue` blocked cross-iteration software pipelining;
// the ~600cy of score math per j4 could never cover next-iteration load
// latency with only 2 waves/SIMD). Straight-line body + unroll 2 lets the
// scheduler hoist iteration n+1's mask/c0/t/vr loads under iteration n's
// compute. VGPR may rise to ~140 -- fine, LDS caps us at 2 blocks/CU; the
// only failure mode is spill (watch FETCH_SIZE >> 82 MB).
// NO launch_bounds min-waves hint (64-VGPR cap -> spill).
__global__ __launch_bounds__(256) void attn_kernel(
    const float* __restrict__ qkv, const float* __restrict__ rpeg,
    const float* __restrict__ mask, const float* __restrict__ c0L,
    const float* __restrict__ tL, float* __restrict__ out)
{
  __shared__ float kvs[2 * LW * HD];   // K then V, 64 KB
  const int b = blockIdx.x;
  const int h = blockIdx.y;
  const int tid = threadIdx.x;
  const size_t rowbase = (size_t)b * LW;

  // stage K (cols 128+h*32) and V (cols 256+h*32) into LDS
  for (int it = 0; it < 8; ++it) {
    int f = tid + 256 * it;            // 0..2047
    int j = f >> 3, d4 = f & 7;
    const float* src = qkv + (rowbase + j) * QKVC + h * HD + d4 * 4;
    *(float4*)(&kvs[j * HD + d4 * 4])            = *(const float4*)(src + 128);
    *(float4*)(&kvs[LW * HD + j * HD + d4 * 4])  = *(const float4*)(src + 256);
  }
  __syncthreads();

  const int i  = tid;
  const int i4 = i >> 2;
  float4 q[8];
  {
    const float4* qr = (const float4*)(qkv + (rowbase + i) * QKVC + h * HD);
#pragma unroll
    for (int d = 0; d < 8; ++d) {
      float4 t = qr[d];
      q[d] = make_float4(t.x * SCALE, t.y * SCALE, t.z * SCALE, t.w * SCALE);
    }
  }
  const float4* vrbase =
      (const float4*)(rpeg + ((size_t)h * 4096 + (size_t)i4 * 64) * 96) + 16;
  const float* mrow = mask + ((size_t)b * LW + i) * LW;
  const float* c0p  = c0L + ((size_t)(b * 4 + h) * 64) * 256 + i;
  const float* tp   = tL  + (((size_t)(b * 4 + h) * 64 + i4)) * 256;

  float4 acc[8];
#pragma unroll
  for (int d = 0; d < 8; ++d) acc[d] = make_float4(0.f, 0.f, 0.f, 0.f);
  float l_run = 0.f;

#pragma unroll 2
  for (int j4 = 0; j4 < 64; ++j4) {
    // all loads issued up front; no branch anywhere in the body
    float4 mv = *(const float4*)(mrow + j4 * 4);
    float  c0 = c0p[j4 * 256];
    float4 tv = *(const float4*)(tp + j4 * 4);
    const float4* rp = vrbase + (size_t)j4 * 24;
    float4 vrr[8];
#pragma unroll
    for (int d = 0; d < 8; ++d) vrr[d] = rp[d];

    const float4* kb = (const float4*)(&kvs[j4 * 4 * HD]); // 4 K rows
    float s0 = mv.x + c0 + tv.x;
    float s1 = mv.y + c0 + tv.y;
    float s2 = mv.z + c0 + tv.z;
    float s3 = mv.w + c0 + tv.w;
#pragma unroll
    for (int d = 0; d < 8; ++d) {
      float4 qd = q[d];
      s0 += dot4(qd, kb[d]);
      s1 += dot4(qd, kb[8 + d]);
      s2 += dot4(qd, kb[16 + d]);
      s3 += dot4(qd, kb[24 + d]);
    }

    float p0 = __expf(s0), p1 = __expf(s1);
    float p2 = __expf(s2), p3 = __expf(s3);
    float pool = p0 + p1 + p2 + p3;
    l_run += pool;
    const float4* vb = (const float4*)(&kvs[LW * HD + j4 * 4 * HD]);
#pragma unroll
    for (int d = 0; d < 8; ++d) {
      float4 a  = acc[d];
      float4 v0 = vb[d],      v1 = vb[8 + d];
      float4 v2 = vb[16 + d], v3 = vb[24 + d];
      float4 vr = vrr[d];
      a.x += p0 * v0.x + p1 * v1.x + p2 * v2.x + p3 * v3.x + pool * vr.x;
      a.y += p0 * v0.y + p1 * v1.y + p2 * v2.y + p3 * v3.y + pool * vr.y;
      a.z += p0 * v0.z + p1 * v1.z + p2 * v2.z + p3 * v3.z + pool * vr.z;
      a.w += p0 * v0.w + p1 * v1.w + p2 * v2.w + p3 * v3.w + pool * vr.w;
      acc[d] = a;
    }
  }

  float inv = 1.f / l_run;
  float4* orow = (float4*)(out + (rowbase + i) * (4 * HD) + h * HD);
#pragma unroll
  for (int d = 0; d < 8; ++d)
    orow[d] = make_float4(acc[d].x * inv, acc[d].y * inv,
                          acc[d].z * inv, acc[d].w * inv);
}

extern "C" void kernel_launch(void* const* d_in, const int* in_sizes, int n_in,
                              void* d_out, int out_size, void* d_ws, size_t ws_size,
                              hipStream_t stream) {
  (void)in_sizes; (void)n_in; (void)out_size; (void)ws_size;
  const float* x         = (const float*)d_in[0];
  const float* qkv_w     = (const float*)d_in[1];
  const float* qkv_b     = (const float*)d_in[2];
  const float* rpe_table = (const float*)d_in[3];
  const float* proj_w    = (const float*)d_in[4];
  const float* proj_b    = (const float*)d_in[5];
  const float* attn_mask = (const float*)d_in[6];
  const int*   rel_idx   = (const int*)d_in[7];
  float* out = (float*)d_out;

  float* qkvbuf = (float*)d_ws;                          // 32768*384 fp32 (50.3 MB)
  float* rpeg   = qkvbuf + (size_t)ROWS * QKVC;          // 4*4096*96  (6.3 MB)
  float* attnb  = rpeg + (size_t)4 * 4096 * 96;          // 32768*128  (16.8 MB)
  float* c0L    = attnb + (size_t)ROWS * 128;            // 512*64*256 (33.6 MB)
  float* tL     = c0L + (size_t)512 * 64 * 256;          // 512*64*256 (33.6 MB)

  hipLaunchKernelGGL(rpe_gather_kernel, dim3(6144), dim3(256), 0, stream,
                     rpe_table, rel_idx, rpeg);
  hipLaunchKernelGGL((gemm_nt_bias_v3<QKVC, 128>), dim3(ROWS / 128, QKVC / 128),
                     dim3(256), 0, stream, x, qkv_w, qkv_b, qkvbuf);
  hipLaunchKernelGGL(c0_kernel, dim3(64, 4, 8), dim3(256), 0, stream,
                     qkvbuf, rpeg, c0L);
  hipLaunchKernelGGL(t_kernel, dim3(64, 4, 8), dim3(256), 0, stream,
                     qkvbuf, rpeg, tL);
  hipLaunchKernelGGL(attn_kernel, dim3(NWIN, 4), dim3(256), 0, stream,
                     qkvbuf, rpeg, attn_mask, c0L, tL, attnb);
  hipLaunchKernelGGL((gemm_nt_bias_v3<128, 128>), dim3(ROWS / 128, 1),
                     dim3(256), 0, stream, attnb, proj_w, proj_b, out);
}

// Round 8
// 330.986 us; speedup vs baseline: 1.1544x; 1.1544x over previous
//
#include <hip/hip_runtime.h>
#include <math.h>

constexpr int HD    = 32;     // head dim
constexpr int LW    = 256;    // tokens per window (M * N_CAND)
constexpr int NWIN  = 128;    // number of windows (= B_)
constexpr int ROWS  = NWIN * LW;   // 32768 total rows
constexpr int QKVC  = 384;    // qkv columns
constexpr float SCALE = 0.17677669529663687f;  // 1/sqrt(32)

__device__ inline float dot4(const float4 a, const float4 b) {
  return a.x * b.x + a.y * b.y + a.z * b.z + a.w * b.w;
}

// DPP quad butterfly: xor-1 and xor-2 within each 4-lane quad (pure VALU,
// no LDS pipe). quad_perm encodings: [1,0,3,2]=0xB1, [2,3,0,1]=0x4E.
__device__ inline float qswap1(float x) {
  return __int_as_float(__builtin_amdgcn_update_dpp(
      __float_as_int(x), __float_as_int(x), 0xB1, 0xF, 0xF, true));
}
__device__ inline float qswap2(float x) {
  return __int_as_float(__builtin_amdgcn_update_dpp(
      __float_as_int(x), __float_as_int(x), 0x4E, 0xF, 0xF, true));
}

// ---------------- RPE gather: rpe_g[h][i4*64+j4][0:96] ----------------
// s in [0,32): scale*q_rpe   [32,64): k_rpe   [64,96): v_rpe
__global__ __launch_bounds__(256) void rpe_gather_kernel(
    const float* __restrict__ tab, const int* __restrict__ rel_idx,
    float* __restrict__ out)
{
  int gid = blockIdx.x * 256 + threadIdx.x;   // 4*4096*96 = 1,572,864 exact
  int s   = gid % 96;
  int hp  = gid / 96;
  int p   = hp & 4095;
  int h   = hp >> 12;
  float v = tab[(size_t)rel_idx[p] * 384 + h * 96 + s];
  if (s < 32) v *= SCALE;
  out[gid] = v;
}

// ---------------- C[M,N] = A[M,K] @ W[N,K]^T + bias (LDS dbuf v3) -----------
template <int N, int K>
__global__ __launch_bounds__(256) void gemm_nt_bias_v3(
    const float* __restrict__ A, const float* __restrict__ W,
    const float* __restrict__ bias, float* __restrict__ C)
{
  constexpr int BK  = 8;
  constexpr int NS  = K / BK;
  constexpr int LDP = 144;
  __shared__ float As[2][BK][LDP];
  __shared__ float Ws[2][BK][LDP];

  const int tid  = threadIdx.x;
  const int tx   = tid & 15;          // n-dir, 8 cols each
  const int ty   = tid >> 4;          // m-dir, 8 rows each
  const int srow = tid >> 1;          // staging row 0..127
  const int skk  = (tid & 1) << 2;    // staging k base: 0 or 4
  const int sphys = srow + ((srow >> 5) << 2);

  const float* Ag = A + ((size_t)blockIdx.x * 128 + srow) * K + skk;
  const float* Wg = W + ((size_t)blockIdx.y * 128 + srow) * K + skk;

  float4 ra = *(const float4*)(Ag);
  float4 rw = *(const float4*)(Wg);
  As[0][skk + 0][sphys] = ra.x; As[0][skk + 1][sphys] = ra.y;
  As[0][skk + 2][sphys] = ra.z; As[0][skk + 3][sphys] = ra.w;
  Ws[0][skk + 0][sphys] = rw.x; Ws[0][skk + 1][sphys] = rw.y;
  Ws[0][skk + 2][sphys] = rw.z; Ws[0][skk + 3][sphys] = rw.w;
  __syncthreads();

  const int mA = ty * 8; const int pA = mA + ((mA >> 5) << 2);
  const int mB = tx * 8; const int pB = mB + ((mB >> 5) << 2);

  float acc[8][8] = {};

  for (int s = 0; s < NS; ++s) {
    const int cur = s & 1;
    if (s + 1 < NS) {
      const int k0 = (s + 1) * BK;
      ra = *(const float4*)(Ag + k0);
      rw = *(const float4*)(Wg + k0);
    }
#pragma unroll
    for (int k = 0; k < BK; ++k) {
      float4 a0 = *(const float4*)&As[cur][k][pA];
      float4 a1 = *(const float4*)&As[cur][k][pA + 4];
      float4 b0 = *(const float4*)&Ws[cur][k][pB];
      float4 b1 = *(const float4*)&Ws[cur][k][pB + 4];
      float av[8] = {a0.x, a0.y, a0.z, a0.w, a1.x, a1.y, a1.z, a1.w};
      float bv[8] = {b0.x, b0.y, b0.z, b0.w, b1.x, b1.y, b1.z, b1.w};
#pragma unroll
      for (int i = 0; i < 8; ++i)
#pragma unroll
        for (int j = 0; j < 8; ++j)
          acc[i][j] += av[i] * bv[j];
    }
    if (s + 1 < NS) {
      const int nxt = (s + 1) & 1;
      As[nxt][skk + 0][sphys] = ra.x; As[nxt][skk + 1][sphys] = ra.y;
      As[nxt][skk + 2][sphys] = ra.z; As[nxt][skk + 3][sphys] = ra.w;
      Ws[nxt][skk + 0][sphys] = rw.x; Ws[nxt][skk + 1][sphys] = rw.y;
      Ws[nxt][skk + 2][sphys] = rw.z; Ws[nxt][skk + 3][sphys] = rw.w;
      __syncthreads();
    }
  }

  const int crow = blockIdx.x * 128 + ty * 8;
  const int ccol = blockIdx.y * 128 + tx * 8;
  float4 bb0 = *(const float4*)(bias + ccol);
  float4 bb1 = *(const float4*)(bias + ccol + 4);
#pragma unroll
  for (int i = 0; i < 8; ++i) {
    float4 r0, r1;
    r0.x = acc[i][0] + bb0.x; r0.y = acc[i][1] + bb0.y;
    r0.z = acc[i][2] + bb0.z; r0.w = acc[i][3] + bb0.w;
    r1.x = acc[i][4] + bb1.x; r1.y = acc[i][5] + bb1.y;
    r1.z = acc[i][6] + bb1.z; r1.w = acc[i][7] + bb1.w;
    *(float4*)(C + (size_t)(crow + i) * N + ccol)     = r0;
    *(float4*)(C + (size_t)(crow + i) * N + ccol + 4) = r1;
  }
}

// ---------- fused window attention (v9: quad-split rows, 1024 thr) ----------
// grid (NWIN, 4 heads), 1024 threads. thread = (query row i = tid>>2,
// dim-quarter qt = tid&3, 8 dims each). 16 waves/block, 64 KB LDS ->
// up to 2 blocks x 16 waves = 32 waves/CU (vs 8 for the row-per-thread
// layout that was pinned at 146-190us).
// Score: s_j = (q*s + s*q_rpe).k_j + (q*s).k_rpe + mask.  Each lane computes
// its 8-dim PARTIAL of both dot terms (k_rpe partial folded into each j's
// partial), then one 2-step DPP quad butterfly yields the full s_j in all 4
// lanes -- the rpe terms cost only 2 extra f4 loads + 16 FMA/lane/j4, so the
// separate c0/t kernels (~70us) are DELETED.
// Static-max softmax (|s| <~ 1 -> p = __expf(s); __expf(-1e9)=0 exactly);
// wave-uniform mask skip (wave = 16 rows, region-uniform) kept per v8 lesson.
// PV: each lane accumulates its own 8 dims (no reduce needed).
// Plain __launch_bounds__(1024): VGPR cap 128, est. use ~70-90 -> no spill.
__global__ __launch_bounds__(1024) void attn_kernel(
    const float* __restrict__ qkv, const float* __restrict__ rpeg,
    const float* __restrict__ mask, float* __restrict__ out)
{
  __shared__ float kvs[2 * LW * HD];   // K then V, 64 KB
  const int b = blockIdx.x;
  const int h = blockIdx.y;
  const int tid = threadIdx.x;
  const size_t rowbase = (size_t)b * LW;

  // stage K (cols 128+h*32) and V (cols 256+h*32) into LDS
  for (int it = 0; it < 2; ++it) {
    int f = tid + 1024 * it;           // 0..2047
    int j = f >> 3, d4 = f & 7;
    const float* src = qkv + (rowbase + j) * QKVC + h * HD + d4 * 4;
    *(float4*)(&kvs[j * HD + d4 * 4])            = *(const float4*)(src + 128);
    *(float4*)(&kvs[LW * HD + j * HD + d4 * 4])  = *(const float4*)(src + 256);
  }
  __syncthreads();

  const int i  = tid >> 2;       // query row
  const int qt = tid & 3;        // dim quarter
  const int i4 = i >> 2;
  const int dq = qt * 8;         // dim offset of this lane's slice

  float4 qa, qb;                 // scaled q quarter
  {
    const float* qr = qkv + (rowbase + i) * QKVC + h * HD + dq;
    float4 t0 = *(const float4*)qr;
    float4 t1 = *(const float4*)(qr + 4);
    qa = make_float4(t0.x * SCALE, t0.y * SCALE, t0.z * SCALE, t0.w * SCALE);
    qb = make_float4(t1.x * SCALE, t1.y * SCALE, t1.z * SCALE, t1.w * SCALE);
  }
  // rpeg row for (h, i4, j4): 96 floats = sq[32] | kr[32] | vr[32]
  const float* rbase = rpeg + ((size_t)h * 4096 + (size_t)i4 * 64) * 96 + dq;
  const float* mrow  = mask + ((size_t)b * LW + i) * LW;

  float4 acc0 = make_float4(0.f, 0.f, 0.f, 0.f);
  float4 acc1 = make_float4(0.f, 0.f, 0.f, 0.f);
  float l_run = 0.f;

  for (int j4 = 0; j4 < 64; ++j4) {
    float4 mv = *(const float4*)(mrow + j4 * 4);
    float mm4 = fmaxf(fmaxf(mv.x, mv.y), fmaxf(mv.z, mv.w));
    if (__all(mm4 < -1e8f)) continue;   // whole j4 block masked for this wave

    const float* rp = rbase + (size_t)j4 * 96;
    float4 sqa = *(const float4*)(rp);        // scale*q_rpe quarter
    float4 sqb = *(const float4*)(rp + 4);
    float4 kra = *(const float4*)(rp + 32);   // k_rpe quarter
    float4 krb = *(const float4*)(rp + 36);

    // u = q*s + s*q_rpe (per-quarter); c0 partial = (q*s).k_rpe
    float4 ua = make_float4(qa.x + sqa.x, qa.y + sqa.y, qa.z + sqa.z, qa.w + sqa.w);
    float4 ub = make_float4(qb.x + sqb.x, qb.y + sqb.y, qb.z + sqb.z, qb.w + sqb.w);
    float c0p = dot4(qa, kra) + dot4(qb, krb);

    const float* kb = &kvs[j4 * 4 * HD + dq];
    float4 k0a = *(const float4*)(kb);            float4 k0b = *(const float4*)(kb + 4);
    float4 k1a = *(const float4*)(kb + HD);       float4 k1b = *(const float4*)(kb + HD + 4);
    float4 k2a = *(const float4*)(kb + 2 * HD);   float4 k2b = *(const float4*)(kb + 2 * HD + 4);
    float4 k3a = *(const float4*)(kb + 3 * HD);   float4 k3b = *(const float4*)(kb + 3 * HD + 4);

    float s0 = dot4(ua, k0a) + dot4(ub, k0b) + c0p;
    float s1 = dot4(ua, k1a) + dot4(ub, k1b) + c0p;
    float s2 = dot4(ua, k2a) + dot4(ub, k2b) + c0p;
    float s3 = dot4(ua, k3a) + dot4(ub, k3b) + c0p;

    // quad butterfly: all 4 lanes of this row get the full 32-dim sums
    s0 += qswap1(s0); s0 += qswap2(s0);
    s1 += qswap1(s1); s1 += qswap2(s1);
    s2 += qswap1(s2); s2 += qswap2(s2);
    s3 += qswap1(s3); s3 += qswap2(s3);

    float p0 = __expf(s0 + mv.x);
    float p1 = __expf(s1 + mv.y);
    float p2 = __expf(s2 + mv.z);
    float p3 = __expf(s3 + mv.w);
    float pool = p0 + p1 + p2 + p3;
    l_run += pool;

    float4 vra = *(const float4*)(rp + 64);   // v_rpe quarter
    float4 vrb = *(const float4*)(rp + 68);
    const float* vb = &kvs[LW * HD + j4 * 4 * HD + dq];
    float4 v0a = *(const float4*)(vb);            float4 v0b = *(const float4*)(vb + 4);
    float4 v1a = *(const float4*)(vb + HD);       float4 v1b = *(const float4*)(vb + HD + 4);
    float4 v2a = *(const float4*)(vb + 2 * HD);   float4 v2b = *(const float4*)(vb + 2 * HD + 4);
    float4 v3a = *(const float4*)(vb + 3 * HD);   float4 v3b = *(const float4*)(vb + 3 * HD + 4);

    acc0.x += p0 * v0a.x + p1 * v1a.x + p2 * v2a.x + p3 * v3a.x + pool * vra.x;
    acc0.y += p0 * v0a.y + p1 * v1a.y + p2 * v2a.y + p3 * v3a.y + pool * vra.y;
    acc0.z += p0 * v0a.z + p1 * v1a.z + p2 * v2a.z + p3 * v3a.z + pool * vra.z;
    acc0.w += p0 * v0a.w + p1 * v1a.w + p2 * v2a.w + p3 * v3a.w + pool * vra.w;
    acc1.x += p0 * v0b.x + p1 * v1b.x + p2 * v2b.x + p3 * v3b.x + pool * vrb.x;
    acc1.y += p0 * v0b.y + p1 * v1b.y + p2 * v2b.y + p3 * v3b.y + pool * vrb.y;
    acc1.z += p0 * v0b.z + p1 * v1b.z + p2 * v2b.z + p3 * v3b.z + pool * vrb.z;
    acc1.w += p0 * v0b.w + p1 * v1b.w + p2 * v2b.w + p3 * v3b.w + pool * vrb.w;
  }

  float inv = 1.f / l_run;   // identical in all 4 quad lanes
  float* orow = out + (rowbase + i) * (4 * HD) + h * HD + dq;
  *(float4*)(orow)     = make_float4(acc0.x * inv, acc0.y * inv,
                                     acc0.z * inv, acc0.w * inv);
  *(float4*)(orow + 4) = make_float4(acc1.x * inv, acc1.y * inv,
                                     acc1.z * inv, acc1.w * inv);
}

extern "C" void kernel_launch(void* const* d_in, const int* in_sizes, int n_in,
                              void* d_out, int out_size, void* d_ws, size_t ws_size,
                              hipStream_t stream) {
  (void)in_sizes; (void)n_in; (void)out_size; (void)ws_size;
  const float* x         = (const float*)d_in[0];
  const float* qkv_w     = (const float*)d_in[1];
  const float* qkv_b     = (const float*)d_in[2];
  const float* rpe_table = (const float*)d_in[3];
  const float* proj_w    = (const float*)d_in[4];
  const float* proj_b    = (const float*)d_in[5];
  const float* attn_mask = (const float*)d_in[6];
  const int*   rel_idx   = (const int*)d_in[7];
  float* out = (float*)d_out;

  float* qkvbuf = (float*)d_ws;                          // 32768*384 fp32 (50.3 MB)
  float* rpeg   = qkvbuf + (size_t)ROWS * QKVC;          // 4*4096*96  (6.3 MB)
  float* attnb  = rpeg + (size_t)4 * 4096 * 96;          // 32768*128  (16.8 MB)

  hipLaunchKernelGGL(rpe_gather_kernel, dim3(6144), dim3(256), 0, stream,
                     rpe_table, rel_idx, rpeg);
  hipLaunchKernelGGL((gemm_nt_bias_v3<QKVC, 128>), dim3(ROWS / 128, QKVC / 128),
                     dim3(256), 0, stream, x, qkv_w, qkv_b, qkvbuf);
  hipLaunchKernelGGL(attn_kernel, dim3(NWIN, 4), dim3(1024), 0, stream,
                     qkvbuf, rpeg, attn_mask, attnb);
  hipLaunchKernelGGL((gemm_nt_bias_v3<128, 128>), dim3(ROWS / 128, 1),
                     dim3(256), 0, stream, attnb, proj_w, proj_b, out);
}